// Round 16
// baseline (522.505 us; speedup 1.0000x reference)
//
#include <hip/hip_runtime.h>
#include <hip/hip_bf16.h>

#define T_TOK 4096
#define D_MODEL 1024
#define I_DIM 2048
#define E_EXP 16

typedef __bf16 bf16x8 __attribute__((ext_vector_type(8)));
typedef float f32x4 __attribute__((ext_vector_type(4)));

__device__ __forceinline__ bf16x8 pack8(f32x4 a, f32x4 b) {
    bf16x8 r;
    r[0] = (__bf16)a[0]; r[1] = (__bf16)a[1]; r[2] = (__bf16)a[2]; r[3] = (__bf16)a[3];
    r[4] = (__bf16)b[0]; r[5] = (__bf16)b[1]; r[6] = (__bf16)b[2]; r[7] = (__bf16)b[3];
    return r;
}

__device__ __forceinline__ void gl2lds(const __bf16* src, __bf16* dst) {
    __builtin_amdgcn_global_load_lds(
        (const __attribute__((address_space(1))) unsigned int*)src,
        (__attribute__((address_space(3))) unsigned int*)dst, 16, 0, 0);
}

__device__ __forceinline__ f32x4 mf(bf16x8 a, bf16x8 b, f32x4 c) {
    return __builtin_amdgcn_mfma_f32_16x16x32_bf16(a, b, c, 0, 0, 0);
}

__global__ __launch_bounds__(256) void cvt_kernel(
    const float* __restrict__ in, __bf16* __restrict__ out, int n8)
{
    const int stride = gridDim.x * 256;
    for (int i = blockIdx.x * 256 + threadIdx.x; i < n8; i += stride) {
        f32x4 a = ((const f32x4*)in)[i * 2];
        f32x4 b = ((const f32x4*)in)[i * 2 + 1];
        ((bf16x8*)out)[i] = pack8(a, b);
    }
}

// ---------------- Router phase 1 (FUSED): routing + x/ws bf16 converts --------
__global__ __launch_bounds__(256) void router_fused_kernel(
    const float* __restrict__ x, const float* __restrict__ rw,
    unsigned int* __restrict__ choices, float* __restrict__ gate4,
    __bf16* __restrict__ x_bf, const float* __restrict__ wsw, __bf16* __restrict__ ws_bf)
{
    const int b = blockIdx.x;
    if (b >= 1280) {                    // ---- ws cvt: 2048 blocks
        const int n8 = E_EXP * 2 * I_DIM * D_MODEL / 8;
        for (int i = (b - 1280) * 256 + threadIdx.x; i < n8; i += 2048 * 256) {
            f32x4 a = ((const f32x4*)wsw)[i * 2];
            f32x4 c = ((const f32x4*)wsw)[i * 2 + 1];
            ((bf16x8*)ws_bf)[i] = pack8(a, c);
        }
        return;
    }
    if (b >= 1024) {                    // ---- x cvt: 256 blocks
        const int n8 = T_TOK * D_MODEL / 8;
        for (int i = (b - 1024) * 256 + threadIdx.x; i < n8; i += 256 * 256) {
            f32x4 a = ((const f32x4*)x)[i * 2];
            f32x4 c = ((const f32x4*)x)[i * 2 + 1];
            ((bf16x8*)x_bf)[i] = pack8(a, c);
        }
        return;
    }
    const int wid = threadIdx.x >> 6, lane = threadIdx.x & 63;
    const int t = b * 4 + wid;
    const int e = lane & 15, part = lane >> 4;

    const float* xr = x + (size_t)t * D_MODEL + part * 256;
    const float* wr = rw + (size_t)e * D_MODEL + part * 256;
    double acc = 0.0;
    #pragma unroll 4
    for (int i = 0; i < 256; i += 4) {
        f32x4 xv = *(const f32x4*)(xr + i);
        f32x4 wv = *(const f32x4*)(wr + i);
        acc += (double)xv[0] * wv[0] + (double)xv[1] * wv[1]
             + (double)xv[2] * wv[2] + (double)xv[3] * wv[3];
    }
    acc += __shfl_xor(acc, 16, 64);
    acc += __shfl_xor(acc, 32, 64);

    __shared__ float logits[4][16];
    if (lane < 16) logits[wid][lane] = (float)acc;
    __syncthreads();

    if (lane == 0) {
        float l[16];
        #pragma unroll
        for (int i = 0; i < 16; i++) l[i] = logits[wid][i];
        int idx[4]; float val[4];
        unsigned taken = 0;
        for (int k = 0; k < 4; k++) {
            int best = 0; float bv = -1e30f;
            for (int i = 0; i < 16; i++)
                if (!((taken >> i) & 1) && l[i] > bv) { bv = l[i]; best = i; }
            idx[k] = best; val[k] = bv; taken |= (1u << best);
        }
        const float m = val[0];
        float w[4], s = 0.f;
        for (int k = 0; k < 4; k++) { w[k] = __expf(val[k] - m); s += w[k]; }
        choices[t] = (unsigned)idx[0] | ((unsigned)idx[1] << 4)
                   | ((unsigned)idx[2] << 8) | ((unsigned)idx[3] << 12);
        f32x4 g = {w[0] / s, w[1] / s, w[2] / s, w[3] / s};
        *(f32x4*)(gate4 + t * 4) = g;
    }
}

// ---------------- Router phase 2: per-expert lists via ballot prefix sums -----
__global__ __launch_bounds__(256) void build_lists_kernel(
    const unsigned int* __restrict__ choices, const float* __restrict__ gate4,
    int* __restrict__ counts, int* __restrict__ tok_list, float* __restrict__ gate_list,
    int* __restrict__ kidx_list)
{
    const int e = blockIdx.x;
    const int tid = threadIdx.x, lane = tid & 63, w = tid >> 6;
    __shared__ int wave_cnt[4];
    __shared__ int running;
    if (tid == 0) running = 0;
    __syncthreads();
    for (int chunk = 0; chunk < T_TOK; chunk += 256) {
        const int t = chunk + tid;
        const unsigned int ch = choices[t];
        int k = -1;
        #pragma unroll
        for (int kk = 0; kk < 4; ++kk)
            if (((ch >> (4 * kk)) & 15u) == (unsigned)e) k = kk;
        const unsigned long long m = __ballot(k >= 0);
        const int my = __popcll(m & ((1ull << lane) - 1ull));
        if (lane == 0) wave_cnt[w] = __popcll(m);
        __syncthreads();
        int base = running;
        #pragma unroll
        for (int i = 0; i < 4; ++i) if (i < w) base += wave_cnt[i];
        if (k >= 0) {
            const int slot = base + my;
            tok_list[e * T_TOK + slot] = t;
            gate_list[e * T_TOK + slot] = gate4[t * 4 + k];
            kidx_list[e * T_TOK + slot] = k;
        }
        __syncthreads();
        if (tid == 0) running += wave_cnt[0] + wave_cnt[1] + wave_cnt[2] + wave_cnt[3];
        __syncthreads();
    }
    if (tid == 0) counts[e] = running;
}

__global__ void prefix_kernel(const int* __restrict__ counts, int* __restrict__ prefix) {
    if (threadIdx.x == 0) {
        int acc = 0;
        for (int e = 0; e < E_EXP; e++) { prefix[e] = acc; acc += (counts[e] + 255) & ~255; }
        prefix[E_EXP] = acc;
    }
}

// ======================= GEMM1 + SwiGLU — 256x256 8-PHASE =====================
// BM=256 tok x BN=256 B-rows (128 act cols; B-row frag f even=w1, odd=v1 so
// SwiGLU pairs are adjacent acc cols), BK=64, 8 waves (2M x 4N), 128 KB LDS
// double-buffer. Per phase: {ds_reads; 1 half-tile stage (2 gl_lds/wave);
// s_barrier; lgkmcnt(0)+sched_barrier; setprio(1); 16 MFMA; setprio(0);
// s_barrier}. vmcnt(4) only at phases 3/7 — loads stay in flight across
// barriers (T3/T4). Doubles FLOP per LDS-filled byte vs the 128² m97 tile.
__global__ __launch_bounds__(512) void gemm1_kernel(
    const __bf16* __restrict__ xb, const __bf16* __restrict__ wsb,
    const int* __restrict__ counts, const int* __restrict__ prefix,
    const int* __restrict__ tok_list, __bf16* __restrict__ act)
{
    const int q8 = gridDim.x >> 3;                     // 256
    const int lid = (blockIdx.x & 7) * q8 + (blockIdx.x >> 3);
    const int e = lid >> 7;                            // 128 blocks / expert
    const int r = lid & 127;
    const int tileM = r & 7;                           // 0..7 (256 tokens each)
    const int tileN = r >> 3;                          // 0..15 (128 act cols)

    const int count = counts[e];
    if (tileM * 256 >= count) return;

    const int tid = threadIdx.x;
    const int lane = tid & 63, w = tid >> 6;
    const int l15 = lane & 15, q = lane >> 4, l7 = lane & 7;
    const int wm = w >> 2, wn = w & 3;

    __shared__ __bf16 As[2][256 * 64];
    __shared__ __bf16 Bs[2][256 * 64];

    // staging: each wave stages rows w*16+[0,16) of each 128-row half-tile.
    const int rl = lane >> 3;
    const int lc = (lane & 7) ^ rl;            // measured-zero-conflict involution
    const __bf16* pA[2][2]; const __bf16* pB[2][2];
    #pragma unroll
    for (int h = 0; h < 2; ++h) {
        #pragma unroll
        for (int i = 0; i < 2; ++i) {
            int grow = tileM * 256 + h * 128 + w * 16 + i * 8 + rl;
            if (grow >= count) grow = count - 1;
            const int token = tok_list[e * T_TOK + grow];
            pA[h][i] = xb + (size_t)token * D_MODEL + lc * 8;
            const int rr = h * 128 + w * 16 + i * 8 + rl;    // tile B-row
            const int f = rr >> 4;
            const int cidx = (f >> 1) * 16 + (rr & 15);
            const int gcol = (f & 1) ? (I_DIM + tileN * 128 + cidx)
                                     : (tileN * 128 + cidx);
            pB[h][i] = wsb + ((size_t)e * 2 * I_DIM + gcol) * D_MODEL + lc * 8;
        }
    }

    #define STGA(bf, h, ko) do { \
        gl2lds(pA[h][0] + (ko), &As[bf][((h) * 128 + w * 16) * 64]); \
        gl2lds(pA[h][1] + (ko), &As[bf][((h) * 128 + w * 16) * 64 + 512]); } while (0)
    #define STGB(bf, h, ko) do { \
        gl2lds(pB[h][0] + (ko), &Bs[bf][((h) * 128 + w * 16) * 64]); \
        gl2lds(pB[h][1] + (ko), &Bs[bf][((h) * 128 + w * 16) * 64 + 512]); } while (0)
    #define BAR()   asm volatile("s_barrier" ::: "memory")
    #define LGKM0() do { asm volatile("s_waitcnt lgkmcnt(0)" ::: "memory"); \
                         __builtin_amdgcn_sched_barrier(0); } while (0)
    #define VM(n)   asm volatile("s_waitcnt vmcnt(" #n ")" ::: "memory")

    f32x4 acc[8][4];
    const f32x4 z = {0.f, 0.f, 0.f, 0.f};
    #pragma unroll
    for (int mi = 0; mi < 8; ++mi)
        #pragma unroll
        for (int nj = 0; nj < 4; ++nj) acc[mi][nj] = z;

    const int c0 = (q ^ l7) * 8, c1 = ((4 + q) ^ l7) * 8;
    const int ar0 = (wm * 128 + l15) * 64;     // + mi*1024
    const int br0 = (wn * 64 + l15) * 64;      // + nj*1024

    // prologue: tile0 full + tile1 {Bh0, Ah0}; keep last 4 loads in flight
    STGA(0, 0, 0); STGA(0, 1, 0); STGB(0, 0, 0); STGB(0, 1, 0);
    STGB(1, 0, 64); STGA(1, 0, 64);
    VM(4); BAR();

    bf16x8 aF[4][2], bE[2][2], bO[2][2];

    for (int it = 0; it < 8; ++it) {
        const int T = it * 2;
        const bool st2 = (it < 7);
        // ================= K-tile T (buf 0) =================
        // P0: reads a0-3 + b0-1 (12); stage T+1:Ah1 -> buf1
        #pragma unroll
        for (int mi = 0; mi < 4; ++mi) {
            aF[mi][0] = *(const bf16x8*)&As[0][ar0 + mi * 1024 + c0];
            aF[mi][1] = *(const bf16x8*)&As[0][ar0 + mi * 1024 + c1];
        }
        #pragma unroll
        for (int nj = 0; nj < 2; ++nj) {
            bE[nj][0] = *(const bf16x8*)&Bs[0][br0 + nj * 1024 + c0];
            bE[nj][1] = *(const bf16x8*)&Bs[0][br0 + nj * 1024 + c1];
        }
        STGA(1, 1, (T + 1) * 64);
        BAR(); LGKM0();
        __builtin_amdgcn_s_setprio(1);
        #pragma unroll
        for (int mi = 0; mi < 4; ++mi)
            #pragma unroll
            for (int nj = 0; nj < 2; ++nj) {
                acc[mi][nj] = mf(aF[mi][0], bE[nj][0], acc[mi][nj]);
                acc[mi][nj] = mf(aF[mi][1], bE[nj][1], acc[mi][nj]);
            }
        __builtin_amdgcn_s_setprio(0);
        BAR();
        // P1: reads b2-3 (4); stage T+1:Bh1
        #pragma unroll
        for (int nj = 0; nj < 2; ++nj) {
            bO[nj][0] = *(const bf16x8*)&Bs[0][br0 + (2 + nj) * 1024 + c0];
            bO[nj][1] = *(const bf16x8*)&Bs[0][br0 + (2 + nj) * 1024 + c1];
        }
        STGB(1, 1, (T + 1) * 64);
        BAR(); LGKM0();
        __builtin_amdgcn_s_setprio(1);
        #pragma unroll
        for (int mi = 0; mi < 4; ++mi)
            #pragma unroll
            for (int nj = 0; nj < 2; ++nj) {
                acc[mi][2 + nj] = mf(aF[mi][0], bO[nj][0], acc[mi][2 + nj]);
                acc[mi][2 + nj] = mf(aF[mi][1], bO[nj][1], acc[mi][2 + nj]);
            }
        __builtin_amdgcn_s_setprio(0);
        BAR();
        // P2: reads a4-7 (8); stage T+2:Bh0 -> buf0
        #pragma unroll
        for (int mi = 0; mi < 4; ++mi) {
            aF[mi][0] = *(const bf16x8*)&As[0][ar0 + (4 + mi) * 1024 + c0];
            aF[mi][1] = *(const bf16x8*)&As[0][ar0 + (4 + mi) * 1024 + c1];
        }
        if (st2) STGB(0, 0, (T + 2) * 64);
        BAR(); LGKM0();
        __builtin_amdgcn_s_setprio(1);
        #pragma unroll
        for (int mi = 0; mi < 4; ++mi)
            #pragma unroll
            for (int nj = 0; nj < 2; ++nj) {
                acc[4 + mi][nj] = mf(aF[mi][0], bE[nj][0], acc[4 + mi][nj]);
                acc[4 + mi][nj] = mf(aF[mi][1], bE[nj][1], acc[4 + mi][nj]);
            }
        __builtin_amdgcn_s_setprio(0);
        BAR();
        // P3: no reads; stage T+2:Ah0; GATE vmcnt(4)
        if (st2) STGA(0, 0, (T + 2) * 64);
        BAR(); LGKM0();
        __builtin_amdgcn_s_setprio(1);
        #pragma unroll
        for (int mi = 0; mi < 4; ++mi)
            #pragma unroll
            for (int nj = 0; nj < 2; ++nj) {
                acc[4 + mi][2 + nj] = mf(aF[mi][0], bO[nj][0], acc[4 + mi][2 + nj]);
                acc[4 + mi][2 + nj] = mf(aF[mi][1], bO[nj][1], acc[4 + mi][2 + nj]);
            }
        __builtin_amdgcn_s_setprio(0);
        if (it == 7) { VM(0); } else { VM(4); }
        BAR();
        // ================= K-tile T+1 (buf 1) =================
        // P4: reads a0-3 + b0-1; stage T+2:Ah1 -> buf0
        #pragma unroll
        for (int mi = 0; mi < 4; ++mi) {
            aF[mi][0] = *(const bf16x8*)&As[1][ar0 + mi * 1024 + c0];
            aF[mi][1] = *(const bf16x8*)&As[1][ar0 + mi * 1024 + c1];
        }
        #pragma unroll
        for (int nj = 0; nj < 2; ++nj) {
            bE[nj][0] = *(const bf16x8*)&Bs[1][br0 + nj * 1024 + c0];
            bE[nj][1] = *(const bf16x8*)&Bs[1][br0 + nj * 1024 + c1];
        }
        if (st2) STGA(0, 1, (T + 2) * 64);
        BAR(); LGKM0();
        __builtin_amdgcn_s_setprio(1);
        #pragma unroll
        for (int mi = 0; mi < 4; ++mi)
            #pragma unroll
            for (int nj = 0; nj < 2; ++nj) {
                acc[mi][nj] = mf(aF[mi][0], bE[nj][0], acc[mi][nj]);
                acc[mi][nj] = mf(aF[mi][1], bE[nj][1], acc[mi][nj]);
            }
        __builtin_amdgcn_s_setprio(0);
        BAR();
        // P5: reads b2-3; stage T+2:Bh1
        #pragma unroll
        for (int nj = 0; nj < 2; ++nj) {
            bO[nj][0] = *(const bf16x8*)&Bs[1][br0 + (2 + nj) * 1024 + c0];
            bO[nj][1] = *(const bf16x8*)&Bs[1][br0 + (2 + nj) * 1024 + c1];
        }
        if (st2) STGB(0, 1, (T + 2) * 64);
        BAR(); LGKM0();
        __builtin_amdgcn_s_setprio(1);
        #pragma unroll
        for (int mi = 0; mi < 4; ++mi)
            #pragma unroll
            for (int nj = 0; nj < 2; ++nj) {
                acc[mi][2 + nj] = mf(aF[mi][0], bO[nj][0], acc[mi][2 + nj]);
                acc[mi][2 + nj] = mf(aF[mi][1], bO[nj][1], acc[mi][2 + nj]);
            }
        __builtin_amdgcn_s_setprio(0);
        BAR();
        // P6: reads a4-7; stage T+3:Bh0 -> buf1
        #pragma unroll
        for (int mi = 0; mi < 4; ++mi) {
            aF[mi][0] = *(const bf16x8*)&As[1][ar0 + (4 + mi) * 1024 + c0];
            aF[mi][1] = *(const bf16x8*)&As[1][ar0 + (4 + mi) * 1024 + c1];
        }
        if (st2) STGB(1, 0, (T + 3) * 64);
        BAR(); LGKM0();
        __builtin_amdgcn_s_setprio(1);
        #pragma unroll
        for (int mi = 0; mi < 4; ++mi)
            #pragma unroll
            for (int nj = 0; nj < 2; ++nj) {
                acc[4 + mi][nj] = mf(aF[mi][0], bE[nj][0], acc[4 + mi][nj]);
                acc[4 + mi][nj] = mf(aF[mi][1], bE[nj][1], acc[4 + mi][nj]);
            }
        __builtin_amdgcn_s_setprio(0);
        BAR();
        // P7: no reads; stage T+3:Ah0; GATE vmcnt(4)
        if (st2) STGA(1, 0, (T + 3) * 64);
        BAR(); LGKM0();
        __builtin_amdgcn_s_setprio(1);
        #pragma unroll
        for (int mi = 0; mi < 4; ++mi)
            #pragma unroll
            for (int nj = 0; nj < 2; ++nj) {
                acc[4 + mi][2 + nj] = mf(aF[mi][0], bO[nj][0], acc[4 + mi][2 + nj]);
                acc[4 + mi][2 + nj] = mf(aF[mi][1], bO[nj][1], acc[4 + mi][2 + nj]);
            }
        __builtin_amdgcn_s_setprio(0);
        if (it == 7) { VM(0); } else { VM(4); }
        BAR();
    }
    #undef STGA
    #undef STGB
    #undef BAR
    #undef LGKM0
    #undef VM

    // epilogue: acc col pairs (2p = w1, 2p+1 = v1) -> act col tileN*128+wn*32+p*16+l15
    const int abase = prefix[e];
    #pragma unroll
    for (int mi = 0; mi < 8; ++mi) {
        #pragma unroll
        for (int j = 0; j < 4; ++j) {
            const int grow = tileM * 256 + wm * 128 + mi * 16 + q * 4 + j;
            if (grow < count) {
                __bf16* arowp = act + (size_t)(abase + grow) * I_DIM
                              + tileN * 128 + wn * 32 + l15;
                #pragma unroll
                for (int p = 0; p < 2; ++p) {
                    const float v1 = acc[mi][2 * p][j];
                    const float v2 = acc[mi][2 * p + 1][j];
                    arowp[p * 16] = (__bf16)(v1 / (1.f + __expf(-v1)) * v2);
                }
            }
        }
    }
}

// ======================= GEMM2 (round-12 proven: bf16 w2, atomic-free) ========
__global__ __launch_bounds__(256, 3) void gemm2_kernel(
    const __bf16* __restrict__ act, const __bf16* __restrict__ w2b,
    const int* __restrict__ counts, const int* __restrict__ prefix,
    const int* __restrict__ tok_list, const float* __restrict__ gate_list,
    const int* __restrict__ kidx_list, float* __restrict__ ypart)
{
    const int q8 = gridDim.x >> 3;                     // 256
    const int lid = (blockIdx.x & 7) * q8 + (blockIdx.x >> 3);
    const int e = lid >> 7;                            // 128 blocks / expert
    const int r = lid & 127;
    const int tileM = r & 15;
    const int tileN = r >> 4;

    const int count = counts[e];
    if (tileM * 128 >= count) return;

    const int tid = threadIdx.x;
    const int lane = tid & 63, w = tid >> 6;
    const int l15 = lane & 15, q = lane >> 4, l7 = lane & 7;
    const int wm = w >> 1, wc = w & 1;
    const int abase = prefix[e];

    __shared__ __bf16 As[128 * 64];
    __shared__ __bf16 Bs[128 * 64];

    const int rl = lane >> 3;
    const int lc = (lane & 7) ^ rl;
    const __bf16* ptrA[4]; const __bf16* ptrB[4];
    #pragma unroll
    for (int i = 0; i < 4; ++i) {
        const int ar = tileM * 128 + w * 32 + i * 8 + rl;
        ptrA[i] = act + (size_t)(abase + ar) * I_DIM + lc * 8;
        const int dcol = tileN * 128 + w * 32 + i * 8 + rl;
        ptrB[i] = w2b + ((size_t)e * D_MODEL + dcol) * I_DIM + lc * 8;
    }
    __bf16* dA = &As[w * 2048];
    __bf16* dB = &Bs[w * 2048];

    #define STAGE(koff) do { \
        _Pragma("unroll") \
        for (int i_ = 0; i_ < 4; ++i_) gl2lds(ptrA[i_] + (koff), dA + i_ * 512); \
        _Pragma("unroll") \
        for (int i_ = 0; i_ < 4; ++i_) gl2lds(ptrB[i_] + (koff), dB + i_ * 512); \
    } while (0)

    f32x4 acc[4][4];
    const f32x4 z = {0.f, 0.f, 0.f, 0.f};
    #pragma unroll
    for (int mi = 0; mi < 4; ++mi)
        #pragma unroll
        for (int nj = 0; nj < 4; ++nj) acc[mi][nj] = z;

    const int c0 = (q ^ l7) * 8, c1 = ((4 + q) ^ l7) * 8;
    const int aoff = (wm * 64 + l15) * 64;
    const int boff = (wc * 64 + l15) * 64;

    STAGE(0);
    for (int kt = 0; kt < 32; ++kt) {
        __syncthreads();
        bf16x8 a0[4], a1[4], b0[4], b1[4];
        #pragma unroll
        for (int mi = 0; mi < 4; ++mi) {
            a0[mi] = *(const bf16x8*)&As[aoff + mi * 1024 + c0];
            a1[mi] = *(const bf16x8*)&As[aoff + mi * 1024 + c1];
        }
        #pragma unroll
        for (int nj = 0; nj < 4; ++nj) {
            b0[nj] = *(const bf16x8*)&Bs[boff + nj * 1024 + c0];
            b1[nj] = *(const bf16x8*)&Bs[boff + nj * 1024 + c1];
        }
        __syncthreads();
        if (kt + 1 < 32) STAGE((kt + 1) * 64);
        #pragma unroll
        for (int mi = 0; mi < 4; ++mi)
            #pragma unroll
            for (int nj = 0; nj < 4; ++nj) {
                acc[mi][nj] = mf(a0[mi], b0[nj], acc[mi][nj]);
                acc[mi][nj] = mf(a1[mi], b1[nj], acc[mi][nj]);
            }
    }
    #undef STAGE

    #pragma unroll
    for (int mi = 0; mi < 4; ++mi) {
        #pragma unroll
        for (int j = 0; j < 4; ++j) {
            const int grow = tileM * 128 + wm * 64 + mi * 16 + q * 4 + j;
            if (grow < count) {
                const int token = tok_list[e * T_TOK + grow];
                const int kk = kidx_list[e * T_TOK + grow];
                const float gate = gate_list[e * T_TOK + grow];
                float* orow = ypart + ((size_t)token * 4 + kk) * D_MODEL + tileN * 128 + wc * 64 + l15;
                #pragma unroll
                for (int nj = 0; nj < 4; ++nj)
                    orow[nj * 16] = gate * acc[mi][nj][j];
            }
        }
    }
}

// ---------------- Combine: out[t] = sum of the token's 4 gated partials ------
__global__ __launch_bounds__(256) void combine_kernel(
    const float* __restrict__ ypart, float* __restrict__ out)
{
    const int t = blockIdx.x;
    const int d = threadIdx.x * 4;
    const float* p = ypart + (size_t)t * 4 * D_MODEL;
    f32x4 s = *(const f32x4*)(p + d);
    s += *(const f32x4*)(p + D_MODEL + d);
    s += *(const f32x4*)(p + 2 * D_MODEL + d);
    s += *(const f32x4*)(p + 3 * D_MODEL + d);
    *(f32x4*)(out + (size_t)t * D_MODEL + d) = s;
}

extern "C" void kernel_launch(void* const* d_in, const int* in_sizes, int n_in,
                              void* d_out, int out_size, void* d_ws, size_t ws_size,
                              hipStream_t stream)
{
    const float* x   = (const float*)d_in[0];   // [4096, 1024]
    const float* rw  = (const float*)d_in[1];   // [16, 1024]
    const float* wsw = (const float*)d_in[2];   // [16, 4096, 1024]
    const float* w2s = (const float*)d_in[3];   // [16, 1024, 2048]
    float* out = (float*)d_out;                 // [4096, 1024] fp32

    char* wsb = (char*)d_ws;
    int* counts        = (int*)wsb;                                  // 64 B
    int* prefix        = (int*)(wsb + 128);                          // 17 ints
    int* tok_list      = (int*)(wsb + 1024);                         // 256 KB
    float* gate_list   = (float*)(wsb + 1024 + E_EXP * T_TOK * 4);   // 256 KB
    unsigned* choices  = (unsigned*)(wsb + 544u * 1024);             // 16 KB
    float* gate4       = (float*)(wsb + 576u * 1024);                // 64 KB
    int* kidx_list     = (int*)(wsb + 640u * 1024);                  // 256 KB
    __bf16* x_bf       = (__bf16*)(wsb + (1u << 20));                // [1, 9) MB
    __bf16* act        = (__bf16*)(wsb + (12u << 20));               // [12, 96) MB
    __bf16* ws_bf      = (__bf16*)(wsb + (96u << 20));               // [96, 230) MB — dead after gemm1
    __bf16* w2_bf      = ws_bf;                                      // [96, 160) MB, written after gemm1
    float* ypart       = (float*)(wsb + (160u << 20));               // [160, 227) MB, written by gemm2

    // fused: router (1024 blocks) + x cvt (256) + ws cvt (2048)
    router_fused_kernel<<<dim3(3328), 256, 0, stream>>>(x, rw, choices, gate4, x_bf, wsw, ws_bf);
    build_lists_kernel<<<dim3(E_EXP), 256, 0, stream>>>(choices, gate4, counts, tok_list, gate_list, kidx_list);
    prefix_kernel<<<1, 64, 0, stream>>>(counts, prefix);

    gemm1_kernel<<<dim3(2048), 512, 0, stream>>>(
        x_bf, ws_bf, counts, prefix, tok_list, act);

    cvt_kernel<<<8192, 256, 0, stream>>>(w2s, w2_bf, E_EXP * D_MODEL * I_DIM / 8);

    gemm2_kernel<<<dim3(2048), 256, 0, stream>>>(
        act, w2_bf, counts, prefix, tok_list, gate_list, kidx_list, ypart);

    combine_kernel<<<dim3(T_TOK), 256, 0, stream>>>(ypart, out);
}

// Round 17
// 444.506 us; speedup vs baseline: 1.1755x; 1.1755x over previous
//
#include <hip/hip_runtime.h>
#include <hip/hip_bf16.h>

#define T_TOK 4096
#define D_MODEL 1024
#define I_DIM 2048
#define E_EXP 16

typedef __bf16 bf16x8 __attribute__((ext_vector_type(8)));
typedef float f32x4 __attribute__((ext_vector_type(4)));

__device__ __forceinline__ bf16x8 pack8(f32x4 a, f32x4 b) {
    bf16x8 r;
    r[0] = (__bf16)a[0]; r[1] = (__bf16)a[1]; r[2] = (__bf16)a[2]; r[3] = (__bf16)a[3];
    r[4] = (__bf16)b[0]; r[5] = (__bf16)b[1]; r[6] = (__bf16)b[2]; r[7] = (__bf16)b[3];
    return r;
}

__device__ __forceinline__ void gl2lds(const __bf16* src, __bf16* dst) {
    __builtin_amdgcn_global_load_lds(
        (const __attribute__((address_space(1))) unsigned int*)src,
        (__attribute__((address_space(3))) unsigned int*)dst, 16, 0, 0);
}

__device__ __forceinline__ f32x4 mf(bf16x8 a, bf16x8 b, f32x4 c) {
    return __builtin_amdgcn_mfma_f32_16x16x32_bf16(a, b, c, 0, 0, 0);
}

__global__ __launch_bounds__(256) void cvt_kernel(
    const float* __restrict__ in, __bf16* __restrict__ out, int n8)
{
    const int stride = gridDim.x * 256;
    for (int i = blockIdx.x * 256 + threadIdx.x; i < n8; i += stride) {
        f32x4 a = ((const f32x4*)in)[i * 2];
        f32x4 b = ((const f32x4*)in)[i * 2 + 1];
        ((bf16x8*)out)[i] = pack8(a, b);
    }
}

// ---------------- Router phase 1 (FUSED): routing + x/ws bf16 converts --------
__global__ __launch_bounds__(256) void router_fused_kernel(
    const float* __restrict__ x, const float* __restrict__ rw,
    unsigned int* __restrict__ choices, float* __restrict__ gate4,
    __bf16* __restrict__ x_bf, const float* __restrict__ wsw, __bf16* __restrict__ ws_bf)
{
    const int b = blockIdx.x;
    if (b >= 1280) {                    // ---- ws cvt: 2048 blocks
        const int n8 = E_EXP * 2 * I_DIM * D_MODEL / 8;
        for (int i = (b - 1280) * 256 + threadIdx.x; i < n8; i += 2048 * 256) {
            f32x4 a = ((const f32x4*)wsw)[i * 2];
            f32x4 c = ((const f32x4*)wsw)[i * 2 + 1];
            ((bf16x8*)ws_bf)[i] = pack8(a, c);
        }
        return;
    }
    if (b >= 1024) {                    // ---- x cvt: 256 blocks
        const int n8 = T_TOK * D_MODEL / 8;
        for (int i = (b - 1024) * 256 + threadIdx.x; i < n8; i += 256 * 256) {
            f32x4 a = ((const f32x4*)x)[i * 2];
            f32x4 c = ((const f32x4*)x)[i * 2 + 1];
            ((bf16x8*)x_bf)[i] = pack8(a, c);
        }
        return;
    }
    const int wid = threadIdx.x >> 6, lane = threadIdx.x & 63;
    const int t = b * 4 + wid;
    const int e = lane & 15, part = lane >> 4;

    const float* xr = x + (size_t)t * D_MODEL + part * 256;
    const float* wr = rw + (size_t)e * D_MODEL + part * 256;
    double acc = 0.0;
    #pragma unroll 4
    for (int i = 0; i < 256; i += 4) {
        f32x4 xv = *(const f32x4*)(xr + i);
        f32x4 wv = *(const f32x4*)(wr + i);
        acc += (double)xv[0] * wv[0] + (double)xv[1] * wv[1]
             + (double)xv[2] * wv[2] + (double)xv[3] * wv[3];
    }
    acc += __shfl_xor(acc, 16, 64);
    acc += __shfl_xor(acc, 32, 64);

    __shared__ float logits[4][16];
    if (lane < 16) logits[wid][lane] = (float)acc;
    __syncthreads();

    if (lane == 0) {
        float l[16];
        #pragma unroll
        for (int i = 0; i < 16; i++) l[i] = logits[wid][i];
        int idx[4]; float val[4];
        unsigned taken = 0;
        for (int k = 0; k < 4; k++) {
            int best = 0; float bv = -1e30f;
            for (int i = 0; i < 16; i++)
                if (!((taken >> i) & 1) && l[i] > bv) { bv = l[i]; best = i; }
            idx[k] = best; val[k] = bv; taken |= (1u << best);
        }
        const float m = val[0];
        float w[4], s = 0.f;
        for (int k = 0; k < 4; k++) { w[k] = __expf(val[k] - m); s += w[k]; }
        choices[t] = (unsigned)idx[0] | ((unsigned)idx[1] << 4)
                   | ((unsigned)idx[2] << 8) | ((unsigned)idx[3] << 12);
        f32x4 g = {w[0] / s, w[1] / s, w[2] / s, w[3] / s};
        *(f32x4*)(gate4 + t * 4) = g;
    }
}

// ---------------- Router phase 2: per-expert lists via ballot prefix sums -----
__global__ __launch_bounds__(256) void build_lists_kernel(
    const unsigned int* __restrict__ choices, const float* __restrict__ gate4,
    int* __restrict__ counts, int* __restrict__ tok_list, float* __restrict__ gate_list,
    int* __restrict__ kidx_list)
{
    const int e = blockIdx.x;
    const int tid = threadIdx.x, lane = tid & 63, w = tid >> 6;
    __shared__ int wave_cnt[4];
    __shared__ int running;
    if (tid == 0) running = 0;
    __syncthreads();
    for (int chunk = 0; chunk < T_TOK; chunk += 256) {
        const int t = chunk + tid;
        const unsigned int ch = choices[t];
        int k = -1;
        #pragma unroll
        for (int kk = 0; kk < 4; ++kk)
            if (((ch >> (4 * kk)) & 15u) == (unsigned)e) k = kk;
        const unsigned long long m = __ballot(k >= 0);
        const int my = __popcll(m & ((1ull << lane) - 1ull));
        if (lane == 0) wave_cnt[w] = __popcll(m);
        __syncthreads();
        int base = running;
        #pragma unroll
        for (int i = 0; i < 4; ++i) if (i < w) base += wave_cnt[i];
        if (k >= 0) {
            const int slot = base + my;
            tok_list[e * T_TOK + slot] = t;
            gate_list[e * T_TOK + slot] = gate4[t * 4 + k];
            kidx_list[e * T_TOK + slot] = k;
        }
        __syncthreads();
        if (tid == 0) running += wave_cnt[0] + wave_cnt[1] + wave_cnt[2] + wave_cnt[3];
        __syncthreads();
    }
    if (tid == 0) counts[e] = running;
}

__global__ void prefix_kernel(const int* __restrict__ counts, int* __restrict__ prefix) {
    if (threadIdx.x == 0) {
        int acc = 0;
        for (int e = 0; e < E_EXP; e++) { prefix[e] = acc; acc += (counts[e] + 255) & ~255; }
        prefix[E_EXP] = acc;
    }
}

// ======================= GEMM1 + SwiGLU (m97 structure, round-12 proven) ======
// 128 tok x 64 act-cols (128 B-rows: 64 w1 + 64 v1), BK=64, 4 waves (2Mx2N),
// SINGLE-buffered 32 KB LDS, 2 x __syncthreads per K-step, gl_lds staging,
// (256,3): VGPR 68, no spill. Runs at ~42 GB/s/CU LDS-fill — measured equal to
// the m201 8-phase ceiling; both 256-tile ports (r3, r16) dropped fill 3x.
__global__ __launch_bounds__(256, 3) void gemm1_kernel(
    const __bf16* __restrict__ xb, const __bf16* __restrict__ wsb,
    const int* __restrict__ counts, const int* __restrict__ prefix,
    const int* __restrict__ tok_list, __bf16* __restrict__ act)
{
    const int q8 = gridDim.x >> 3;                     // 1024
    const int lid = (blockIdx.x & 7) * q8 + (blockIdx.x >> 3);
    const int e = lid >> 9;                            // 512 blocks / expert
    const int r = lid & 511;
    const int tileM = r & 15;                          // 0..15 (2048 tokens)
    const int tileN = r >> 4;                          // 0..31

    const int count = counts[e];
    if (tileM * 128 >= count) return;

    const int tid = threadIdx.x;
    const int lane = tid & 63, w = tid >> 6;
    const int l15 = lane & 15, q = lane >> 4, l7 = lane & 7;
    const int wm = w >> 1, wc = w & 1;

    __shared__ __bf16 As[128 * 64];
    __shared__ __bf16 Bs[128 * 64];

    const int rl = lane >> 3;                  // row within 8-row issue group
    const int lc = (lane & 7) ^ rl;            // logical chunk (involution with row&7)
    const __bf16* ptrA[4]; const __bf16* ptrB[4];
    #pragma unroll
    for (int i = 0; i < 4; ++i) {
        int grow = tileM * 128 + w * 32 + i * 8 + rl;
        if (grow >= count) grow = count - 1;
        const int token = tok_list[e * T_TOK + grow];
        ptrA[i] = xb + (size_t)token * D_MODEL + lc * 8;
        const int sub = w * 32 + i * 8 + rl;   // 0..127; rows 0-63 w1, 64-127 v1
        const int gcol = (sub < 64) ? (tileN * 64 + sub) : (I_DIM + tileN * 64 + (sub - 64));
        ptrB[i] = wsb + ((size_t)e * 2 * I_DIM + gcol) * D_MODEL + lc * 8;
    }
    __bf16* dA = &As[w * 2048];
    __bf16* dB = &Bs[w * 2048];

    #define STAGE(koff) do { \
        _Pragma("unroll") \
        for (int i_ = 0; i_ < 4; ++i_) gl2lds(ptrA[i_] + (koff), dA + i_ * 512); \
        _Pragma("unroll") \
        for (int i_ = 0; i_ < 4; ++i_) gl2lds(ptrB[i_] + (koff), dB + i_ * 512); \
    } while (0)

    f32x4 acc[4][4];
    const f32x4 z = {0.f, 0.f, 0.f, 0.f};
    #pragma unroll
    for (int mi = 0; mi < 4; ++mi)
        #pragma unroll
        for (int nj = 0; nj < 4; ++nj) acc[mi][nj] = z;

    const int c0 = (q ^ l7) * 8, c1 = ((4 + q) ^ l7) * 8;
    const int aoff = (wm * 64 + l15) * 64;     // + mi*1024 + c
    const int boff = (wc * 32 + l15) * 64;     // w1: +nj*1024+c ; v1: +4096+nj*1024+c

    STAGE(0);
    for (int kt = 0; kt < 16; ++kt) {
        __syncthreads();                        // drains vmcnt: tile kt resident
        bf16x8 a0[4], a1[4], b0[4], b1[4];
        #pragma unroll
        for (int mi = 0; mi < 4; ++mi) {
            a0[mi] = *(const bf16x8*)&As[aoff + mi * 1024 + c0];
            a1[mi] = *(const bf16x8*)&As[aoff + mi * 1024 + c1];
        }
        #pragma unroll
        for (int nj = 0; nj < 2; ++nj) {
            b0[nj]     = *(const bf16x8*)&Bs[boff + nj * 1024 + c0];
            b0[nj + 2] = *(const bf16x8*)&Bs[boff + 4096 + nj * 1024 + c0];
            b1[nj]     = *(const bf16x8*)&Bs[boff + nj * 1024 + c1];
            b1[nj + 2] = *(const bf16x8*)&Bs[boff + 4096 + nj * 1024 + c1];
        }
        __syncthreads();                        // frags in regs: LDS free to overwrite
        if (kt + 1 < 16) STAGE((kt + 1) * 64);  // loads fly under the MFMAs
        #pragma unroll
        for (int mi = 0; mi < 4; ++mi)
            #pragma unroll
            for (int nj = 0; nj < 4; ++nj) {
                acc[mi][nj] = mf(a0[mi], b0[nj], acc[mi][nj]);
                acc[mi][nj] = mf(a1[mi], b1[nj], acc[mi][nj]);
            }
    }
    #undef STAGE

    const int abase = prefix[e];
    #pragma unroll
    for (int mi = 0; mi < 4; ++mi) {
        #pragma unroll
        for (int j = 0; j < 4; ++j) {
            const int grow = tileM * 128 + wm * 64 + mi * 16 + q * 4 + j;
            if (grow < count) {
                __bf16* arowp = act + (size_t)(abase + grow) * I_DIM + tileN * 64 + wc * 32 + l15;
                #pragma unroll
                for (int nj = 0; nj < 2; ++nj) {
                    const float v1 = acc[mi][nj][j];
                    const float v2 = acc[mi][nj + 2][j];
                    arowp[nj * 16] = (__bf16)(v1 / (1.f + __expf(-v1)) * v2);
                }
            }
        }
    }
}

// ======================= GEMM2 (round-12 proven: bf16 w2, atomic-free) ========
// 128 rows x 128 d-cols, FULL K=2048 (32 K-steps), single-buffer, (256,3).
// Plain stores of gate*y into ypart[(token*4+kidx)*1024+d]; combine sums 4.
__global__ __launch_bounds__(256, 3) void gemm2_kernel(
    const __bf16* __restrict__ act, const __bf16* __restrict__ w2b,
    const int* __restrict__ counts, const int* __restrict__ prefix,
    const int* __restrict__ tok_list, const float* __restrict__ gate_list,
    const int* __restrict__ kidx_list, float* __restrict__ ypart)
{
    const int q8 = gridDim.x >> 3;                     // 256
    const int lid = (blockIdx.x & 7) * q8 + (blockIdx.x >> 3);
    const int e = lid >> 7;                            // 128 blocks / expert
    const int r = lid & 127;
    const int tileM = r & 15;
    const int tileN = r >> 4;

    const int count = counts[e];
    if (tileM * 128 >= count) return;

    const int tid = threadIdx.x;
    const int lane = tid & 63, w = tid >> 6;
    const int l15 = lane & 15, q = lane >> 4, l7 = lane & 7;
    const int wm = w >> 1, wc = w & 1;
    const int abase = prefix[e];

    __shared__ __bf16 As[128 * 64];
    __shared__ __bf16 Bs[128 * 64];

    const int rl = lane >> 3;
    const int lc = (lane & 7) ^ rl;
    const __bf16* ptrA[4]; const __bf16* ptrB[4];
    #pragma unroll
    for (int i = 0; i < 4; ++i) {
        const int ar = tileM * 128 + w * 32 + i * 8 + rl;
        ptrA[i] = act + (size_t)(abase + ar) * I_DIM + lc * 8;
        const int dcol = tileN * 128 + w * 32 + i * 8 + rl;
        ptrB[i] = w2b + ((size_t)e * D_MODEL + dcol) * I_DIM + lc * 8;
    }
    __bf16* dA = &As[w * 2048];
    __bf16* dB = &Bs[w * 2048];

    #define STAGE(koff) do { \
        _Pragma("unroll") \
        for (int i_ = 0; i_ < 4; ++i_) gl2lds(ptrA[i_] + (koff), dA + i_ * 512); \
        _Pragma("unroll") \
        for (int i_ = 0; i_ < 4; ++i_) gl2lds(ptrB[i_] + (koff), dB + i_ * 512); \
    } while (0)

    f32x4 acc[4][4];
    const f32x4 z = {0.f, 0.f, 0.f, 0.f};
    #pragma unroll
    for (int mi = 0; mi < 4; ++mi)
        #pragma unroll
        for (int nj = 0; nj < 4; ++nj) acc[mi][nj] = z;

    const int c0 = (q ^ l7) * 8, c1 = ((4 + q) ^ l7) * 8;
    const int aoff = (wm * 64 + l15) * 64;
    const int boff = (wc * 64 + l15) * 64;

    STAGE(0);
    for (int kt = 0; kt < 32; ++kt) {
        __syncthreads();
        bf16x8 a0[4], a1[4], b0[4], b1[4];
        #pragma unroll
        for (int mi = 0; mi < 4; ++mi) {
            a0[mi] = *(const bf16x8*)&As[aoff + mi * 1024 + c0];
            a1[mi] = *(const bf16x8*)&As[aoff + mi * 1024 + c1];
        }
        #pragma unroll
        for (int nj = 0; nj < 4; ++nj) {
            b0[nj] = *(const bf16x8*)&Bs[boff + nj * 1024 + c0];
            b1[nj] = *(const bf16x8*)&Bs[boff + nj * 1024 + c1];
        }
        __syncthreads();
        if (kt + 1 < 32) STAGE((kt + 1) * 64);
        #pragma unroll
        for (int mi = 0; mi < 4; ++mi)
            #pragma unroll
            for (int nj = 0; nj < 4; ++nj) {
                acc[mi][nj] = mf(a0[mi], b0[nj], acc[mi][nj]);
                acc[mi][nj] = mf(a1[mi], b1[nj], acc[mi][nj]);
            }
    }
    #undef STAGE

    #pragma unroll
    for (int mi = 0; mi < 4; ++mi) {
        #pragma unroll
        for (int j = 0; j < 4; ++j) {
            const int grow = tileM * 128 + wm * 64 + mi * 16 + q * 4 + j;
            if (grow < count) {
                const int token = tok_list[e * T_TOK + grow];
                const int kk = kidx_list[e * T_TOK + grow];
                const float gate = gate_list[e * T_TOK + grow];
                float* orow = ypart + ((size_t)token * 4 + kk) * D_MODEL + tileN * 128 + wc * 64 + l15;
                #pragma unroll
                for (int nj = 0; nj < 4; ++nj)
                    orow[nj * 16] = gate * acc[mi][nj][j];
            }
        }
    }
}

// ---------------- Combine: out[t] = sum of the token's 4 gated partials ------
__global__ __launch_bounds__(256) void combine_kernel(
    const float* __restrict__ ypart, float* __restrict__ out)
{
    const int t = blockIdx.x;
    const int d = threadIdx.x * 4;
    const float* p = ypart + (size_t)t * 4 * D_MODEL;
    f32x4 s = *(const f32x4*)(p + d);
    s += *(const f32x4*)(p + D_MODEL + d);
    s += *(const f32x4*)(p + 2 * D_MODEL + d);
    s += *(const f32x4*)(p + 3 * D_MODEL + d);
    *(f32x4*)(out + (size_t)t * D_MODEL + d) = s;
}

extern "C" void kernel_launch(void* const* d_in, const int* in_sizes, int n_in,
                              void* d_out, int out_size, void* d_ws, size_t ws_size,
                              hipStream_t stream)
{
    const float* x   = (const float*)d_in[0];   // [4096, 1024]
    const float* rw  = (const float*)d_in[1];   // [16, 1024]
    const float* wsw = (const float*)d_in[2];   // [16, 4096, 1024]
    const float* w2s = (const float*)d_in[3];   // [16, 1024, 2048]
    float* out = (float*)d_out;                 // [4096, 1024] fp32

    char* wsb = (char*)d_ws;
    int* counts        = (int*)wsb;                                  // 64 B
    int* prefix        = (int*)(wsb + 128);                          // 17 ints
    int* tok_list      = (int*)(wsb + 1024);                         // 256 KB
    float* gate_list   = (float*)(wsb + 1024 + E_EXP * T_TOK * 4);   // 256 KB
    unsigned* choices  = (unsigned*)(wsb + 544u * 1024);             // 16 KB
    float* gate4       = (float*)(wsb + 576u * 1024);                // 64 KB
    int* kidx_list     = (int*)(wsb + 640u * 1024);                  // 256 KB
    __bf16* x_bf       = (__bf16*)(wsb + (1u << 20));                // [1, 9) MB
    __bf16* act        = (__bf16*)(wsb + (12u << 20));               // [12, 96) MB
    __bf16* ws_bf      = (__bf16*)(wsb + (96u << 20));               // [96, 230) MB — dead after gemm1
    __bf16* w2_bf      = ws_bf;                                      // [96, 160) MB, written after gemm1
    float* ypart       = (float*)(wsb + (160u << 20));               // [160, 227) MB, written by gemm2

    // fused: router (1024 blocks) + x cvt (256) + ws cvt (2048)
    router_fused_kernel<<<dim3(3328), 256, 0, stream>>>(x, rw, choices, gate4, x_bf, wsw, ws_bf);
    build_lists_kernel<<<dim3(E_EXP), 256, 0, stream>>>(choices, gate4, counts, tok_list, gate_list, kidx_list);
    prefix_kernel<<<1, 64, 0, stream>>>(counts, prefix);

    gemm1_kernel<<<dim3(8192), 256, 0, stream>>>(
        x_bf, ws_bf, counts, prefix, tok_list, act);

    cvt_kernel<<<8192, 256, 0, stream>>>(w2s, w2_bf, E_EXP * D_MODEL * I_DIM / 8);

    gemm2_kernel<<<dim3(2048), 256, 0, stream>>>(
        act, w2_bf, counts, prefix, tok_list, gate_list, kidx_list, ypart);

    combine_kernel<<<dim3(T_TOK), 256, 0, stream>>>(ypart, out);
}

// Round 18
// 433.870 us; speedup vs baseline: 1.2043x; 1.0245x over previous
//
#include <hip/hip_runtime.h>
#include <hip/hip_bf16.h>

#define T_TOK 4096
#define D_MODEL 1024
#define I_DIM 2048
#define E_EXP 16

typedef __bf16 bf16x8 __attribute__((ext_vector_type(8)));
typedef float f32x4 __attribute__((ext_vector_type(4)));

__device__ __forceinline__ bf16x8 pack8(f32x4 a, f32x4 b) {
    bf16x8 r;
    r[0] = (__bf16)a[0]; r[1] = (__bf16)a[1]; r[2] = (__bf16)a[2]; r[3] = (__bf16)a[3];
    r[4] = (__bf16)b[0]; r[5] = (__bf16)b[1]; r[6] = (__bf16)b[2]; r[7] = (__bf16)b[3];
    return r;
}

__device__ __forceinline__ void gl2lds(const __bf16* src, __bf16* dst) {
    __builtin_amdgcn_global_load_lds(
        (const __attribute__((address_space(1))) unsigned int*)src,
        (__attribute__((address_space(3))) unsigned int*)dst, 16, 0, 0);
}

__device__ __forceinline__ f32x4 mf(bf16x8 a, bf16x8 b, f32x4 c) {
    return __builtin_amdgcn_mfma_f32_16x16x32_bf16(a, b, c, 0, 0, 0);
}

__global__ __launch_bounds__(256) void cvt_kernel(
    const float* __restrict__ in, __bf16* __restrict__ out, int n8)
{
    const int stride = gridDim.x * 256;
    for (int i = blockIdx.x * 256 + threadIdx.x; i < n8; i += stride) {
        f32x4 a = ((const f32x4*)in)[i * 2];
        f32x4 b = ((const f32x4*)in)[i * 2 + 1];
        ((bf16x8*)out)[i] = pack8(a, b);
    }
}

// ---------------- Router phase 1 (FUSED): routing + x/ws bf16 converts --------
__global__ __launch_bounds__(256) void router_fused_kernel(
    const float* __restrict__ x, const float* __restrict__ rw,
    unsigned int* __restrict__ choices, float* __restrict__ gate4,
    __bf16* __restrict__ x_bf, const float* __restrict__ wsw, __bf16* __restrict__ ws_bf)
{
    const int b = blockIdx.x;
    if (b >= 1280) {                    // ---- ws cvt: 2048 blocks
        const int n8 = E_EXP * 2 * I_DIM * D_MODEL / 8;
        for (int i = (b - 1280) * 256 + threadIdx.x; i < n8; i += 2048 * 256) {
            f32x4 a = ((const f32x4*)wsw)[i * 2];
            f32x4 c = ((const f32x4*)wsw)[i * 2 + 1];
            ((bf16x8*)ws_bf)[i] = pack8(a, c);
        }
        return;
    }
    if (b >= 1024) {                    // ---- x cvt: 256 blocks
        const int n8 = T_TOK * D_MODEL / 8;
        for (int i = (b - 1024) * 256 + threadIdx.x; i < n8; i += 256 * 256) {
            f32x4 a = ((const f32x4*)x)[i * 2];
            f32x4 c = ((const f32x4*)x)[i * 2 + 1];
            ((bf16x8*)x_bf)[i] = pack8(a, c);
        }
        return;
    }
    const int wid = threadIdx.x >> 6, lane = threadIdx.x & 63;
    const int t = b * 4 + wid;
    const int e = lane & 15, part = lane >> 4;

    const float* xr = x + (size_t)t * D_MODEL + part * 256;
    const float* wr = rw + (size_t)e * D_MODEL + part * 256;
    double acc = 0.0;
    #pragma unroll 4
    for (int i = 0; i < 256; i += 4) {
        f32x4 xv = *(const f32x4*)(xr + i);
        f32x4 wv = *(const f32x4*)(wr + i);
        acc += (double)xv[0] * wv[0] + (double)xv[1] * wv[1]
             + (double)xv[2] * wv[2] + (double)xv[3] * wv[3];
    }
    acc += __shfl_xor(acc, 16, 64);
    acc += __shfl_xor(acc, 32, 64);

    __shared__ float logits[4][16];
    if (lane < 16) logits[wid][lane] = (float)acc;
    __syncthreads();

    if (lane == 0) {
        float l[16];
        #pragma unroll
        for (int i = 0; i < 16; i++) l[i] = logits[wid][i];
        int idx[4]; float val[4];
        unsigned taken = 0;
        for (int k = 0; k < 4; k++) {
            int best = 0; float bv = -1e30f;
            for (int i = 0; i < 16; i++)
                if (!((taken >> i) & 1) && l[i] > bv) { bv = l[i]; best = i; }
            idx[k] = best; val[k] = bv; taken |= (1u << best);
        }
        const float m = val[0];
        float w[4], s = 0.f;
        for (int k = 0; k < 4; k++) { w[k] = __expf(val[k] - m); s += w[k]; }
        choices[t] = (unsigned)idx[0] | ((unsigned)idx[1] << 4)
                   | ((unsigned)idx[2] << 8) | ((unsigned)idx[3] << 12);
        f32x4 g = {w[0] / s, w[1] / s, w[2] / s, w[3] / s};
        *(f32x4*)(gate4 + t * 4) = g;
    }
}

// ---------------- Router phase 2: per-expert lists via ballot prefix sums -----
__global__ __launch_bounds__(256) void build_lists_kernel(
    const unsigned int* __restrict__ choices, const float* __restrict__ gate4,
    int* __restrict__ counts, int* __restrict__ tok_list, float* __restrict__ gate_list,
    int* __restrict__ kidx_list)
{
    const int e = blockIdx.x;
    const int tid = threadIdx.x, lane = tid & 63, w = tid >> 6;
    __shared__ int wave_cnt[4];
    __shared__ int running;
    if (tid == 0) running = 0;
    __syncthreads();
    for (int chunk = 0; chunk < T_TOK; chunk += 256) {
        const int t = chunk + tid;
        const unsigned int ch = choices[t];
        int k = -1;
        #pragma unroll
        for (int kk = 0; kk < 4; ++kk)
            if (((ch >> (4 * kk)) & 15u) == (unsigned)e) k = kk;
        const unsigned long long m = __ballot(k >= 0);
        const int my = __popcll(m & ((1ull << lane) - 1ull));
        if (lane == 0) wave_cnt[w] = __popcll(m);
        __syncthreads();
        int base = running;
        #pragma unroll
        for (int i = 0; i < 4; ++i) if (i < w) base += wave_cnt[i];
        if (k >= 0) {
            const int slot = base + my;
            tok_list[e * T_TOK + slot] = t;
            gate_list[e * T_TOK + slot] = gate4[t * 4 + k];
            kidx_list[e * T_TOK + slot] = k;
        }
        __syncthreads();
        if (tid == 0) running += wave_cnt[0] + wave_cnt[1] + wave_cnt[2] + wave_cnt[3];
        __syncthreads();
    }
    if (tid == 0) counts[e] = running;
}

__global__ void prefix_kernel(const int* __restrict__ counts, int* __restrict__ prefix) {
    if (threadIdx.x == 0) {
        int acc = 0;
        for (int e = 0; e < E_EXP; e++) { prefix[e] = acc; acc += (counts[e] + 255) & ~255; }
        prefix[E_EXP] = acc;
    }
}

// ======================= GEMM1 + SwiGLU (m97 structure, round-12 proven) ======
// 128 tok x 64 act-cols, BK=64, 4 waves, single-buffered 32 KB LDS, gl_lds,
// (256,3): VGPR 68, no spill. Blocks >= 8192 (when present) stream-convert
// w2s -> w2_bf (disjoint region) in this dispatch's scheduling tail — the
// 33 us serial cvt_w2 dispatch disappears; gemm2 waits on the whole dispatch.
__global__ __launch_bounds__(256, 3) void gemm1_kernel(
    const __bf16* __restrict__ xb, const __bf16* __restrict__ wsb,
    const int* __restrict__ counts, const int* __restrict__ prefix,
    const int* __restrict__ tok_list, __bf16* __restrict__ act,
    const float* __restrict__ w2s, __bf16* __restrict__ w2_out)
{
    if (blockIdx.x >= 8192) {           // ---- fused w2 cvt tail (2048 blocks)
        const int n8 = E_EXP * D_MODEL * I_DIM / 8;        // 4194304
        for (int i = (blockIdx.x - 8192) * 256 + threadIdx.x; i < n8; i += 2048 * 256) {
            f32x4 a = ((const f32x4*)w2s)[i * 2];
            f32x4 c = ((const f32x4*)w2s)[i * 2 + 1];
            ((bf16x8*)w2_out)[i] = pack8(a, c);
        }
        return;
    }
    const int q8 = 1024;                               // 8192 gemm blocks / 8 XCDs
    const int lid = ((int)blockIdx.x & 7) * q8 + ((int)blockIdx.x >> 3);
    const int e = lid >> 9;                            // 512 blocks / expert
    const int r = lid & 511;
    const int tileM = r & 15;                          // 0..15 (2048 tokens)
    const int tileN = r >> 4;                          // 0..31

    const int count = counts[e];
    if (tileM * 128 >= count) return;

    const int tid = threadIdx.x;
    const int lane = tid & 63, w = tid >> 6;
    const int l15 = lane & 15, q = lane >> 4, l7 = lane & 7;
    const int wm = w >> 1, wc = w & 1;

    __shared__ __bf16 As[128 * 64];
    __shared__ __bf16 Bs[128 * 64];

    const int rl = lane >> 3;                  // row within 8-row issue group
    const int lc = (lane & 7) ^ rl;            // logical chunk (involution with row&7)
    const __bf16* ptrA[4]; const __bf16* ptrB[4];
    #pragma unroll
    for (int i = 0; i < 4; ++i) {
        int grow = tileM * 128 + w * 32 + i * 8 + rl;
        if (grow >= count) grow = count - 1;
        const int token = tok_list[e * T_TOK + grow];
        ptrA[i] = xb + (size_t)token * D_MODEL + lc * 8;
        const int sub = w * 32 + i * 8 + rl;   // 0..127; rows 0-63 w1, 64-127 v1
        const int gcol = (sub < 64) ? (tileN * 64 + sub) : (I_DIM + tileN * 64 + (sub - 64));
        ptrB[i] = wsb + ((size_t)e * 2 * I_DIM + gcol) * D_MODEL + lc * 8;
    }
    __bf16* dA = &As[w * 2048];
    __bf16* dB = &Bs[w * 2048];

    #define STAGE(koff) do { \
        _Pragma("unroll") \
        for (int i_ = 0; i_ < 4; ++i_) gl2lds(ptrA[i_] + (koff), dA + i_ * 512); \
        _Pragma("unroll") \
        for (int i_ = 0; i_ < 4; ++i_) gl2lds(ptrB[i_] + (koff), dB + i_ * 512); \
    } while (0)

    f32x4 acc[4][4];
    const f32x4 z = {0.f, 0.f, 0.f, 0.f};
    #pragma unroll
    for (int mi = 0; mi < 4; ++mi)
        #pragma unroll
        for (int nj = 0; nj < 4; ++nj) acc[mi][nj] = z;

    const int c0 = (q ^ l7) * 8, c1 = ((4 + q) ^ l7) * 8;
    const int aoff = (wm * 64 + l15) * 64;     // + mi*1024 + c
    const int boff = (wc * 32 + l15) * 64;     // w1: +nj*1024+c ; v1: +4096+nj*1024+c

    STAGE(0);
    for (int kt = 0; kt < 16; ++kt) {
        __syncthreads();                        // drains vmcnt: tile kt resident
        bf16x8 a0[4], a1[4], b0[4], b1[4];
        #pragma unroll
        for (int mi = 0; mi < 4; ++mi) {
            a0[mi] = *(const bf16x8*)&As[aoff + mi * 1024 + c0];
            a1[mi] = *(const bf16x8*)&As[aoff + mi * 1024 + c1];
        }
        #pragma unroll
        for (int nj = 0; nj < 2; ++nj) {
            b0[nj]     = *(const bf16x8*)&Bs[boff + nj * 1024 + c0];
            b0[nj + 2] = *(const bf16x8*)&Bs[boff + 4096 + nj * 1024 + c0];
            b1[nj]     = *(const bf16x8*)&Bs[boff + nj * 1024 + c1];
            b1[nj + 2] = *(const bf16x8*)&Bs[boff + 4096 + nj * 1024 + c1];
        }
        __syncthreads();                        // frags in regs: LDS free to overwrite
        if (kt + 1 < 16) STAGE((kt + 1) * 64);  // loads fly under the MFMAs
        #pragma unroll
        for (int mi = 0; mi < 4; ++mi)
            #pragma unroll
            for (int nj = 0; nj < 4; ++nj) {
                acc[mi][nj] = mf(a0[mi], b0[nj], acc[mi][nj]);
                acc[mi][nj] = mf(a1[mi], b1[nj], acc[mi][nj]);
            }
    }
    #undef STAGE

    const int abase = prefix[e];
    #pragma unroll
    for (int mi = 0; mi < 4; ++mi) {
        #pragma unroll
        for (int j = 0; j < 4; ++j) {
            const int grow = tileM * 128 + wm * 64 + mi * 16 + q * 4 + j;
            if (grow < count) {
                __bf16* arowp = act + (size_t)(abase + grow) * I_DIM + tileN * 64 + wc * 32 + l15;
                #pragma unroll
                for (int nj = 0; nj < 2; ++nj) {
                    const float v1 = acc[mi][nj][j];
                    const float v2 = acc[mi][nj + 2][j];
                    arowp[nj * 16] = (__bf16)(v1 / (1.f + __expf(-v1)) * v2);
                }
            }
        }
    }
}

// ======================= GEMM2 (round-12 proven: bf16 w2, atomic-free) ========
__global__ __launch_bounds__(256, 3) void gemm2_kernel(
    const __bf16* __restrict__ act, const __bf16* __restrict__ w2b,
    const int* __restrict__ counts, const int* __restrict__ prefix,
    const int* __restrict__ tok_list, const float* __restrict__ gate_list,
    const int* __restrict__ kidx_list, float* __restrict__ ypart)
{
    const int q8 = gridDim.x >> 3;                     // 256
    const int lid = (blockIdx.x & 7) * q8 + (blockIdx.x >> 3);
    const int e = lid >> 7;                            // 128 blocks / expert
    const int r = lid & 127;
    const int tileM = r & 15;
    const int tileN = r >> 4;

    const int count = counts[e];
    if (tileM * 128 >= count) return;

    const int tid = threadIdx.x;
    const int lane = tid & 63, w = tid >> 6;
    const int l15 = lane & 15, q = lane >> 4, l7 = lane & 7;
    const int wm = w >> 1, wc = w & 1;
    const int abase = prefix[e];

    __shared__ __bf16 As[128 * 64];
    __shared__ __bf16 Bs[128 * 64];

    const int rl = lane >> 3;
    const int lc = (lane & 7) ^ rl;
    const __bf16* ptrA[4]; const __bf16* ptrB[4];
    #pragma unroll
    for (int i = 0; i < 4; ++i) {
        const int ar = tileM * 128 + w * 32 + i * 8 + rl;
        ptrA[i] = act + (size_t)(abase + ar) * I_DIM + lc * 8;
        const int dcol = tileN * 128 + w * 32 + i * 8 + rl;
        ptrB[i] = w2b + ((size_t)e * D_MODEL + dcol) * I_DIM + lc * 8;
    }
    __bf16* dA = &As[w * 2048];
    __bf16* dB = &Bs[w * 2048];

    #define STAGE(koff) do { \
        _Pragma("unroll") \
        for (int i_ = 0; i_ < 4; ++i_) gl2lds(ptrA[i_] + (koff), dA + i_ * 512); \
        _Pragma("unroll") \
        for (int i_ = 0; i_ < 4; ++i_) gl2lds(ptrB[i_] + (koff), dB + i_ * 512); \
    } while (0)

    f32x4 acc[4][4];
    const f32x4 z = {0.f, 0.f, 0.f, 0.f};
    #pragma unroll
    for (int mi = 0; mi < 4; ++mi)
        #pragma unroll
        for (int nj = 0; nj < 4; ++nj) acc[mi][nj] = z;

    const int c0 = (q ^ l7) * 8, c1 = ((4 + q) ^ l7) * 8;
    const int aoff = (wm * 64 + l15) * 64;
    const int boff = (wc * 64 + l15) * 64;

    STAGE(0);
    for (int kt = 0; kt < 32; ++kt) {
        __syncthreads();
        bf16x8 a0[4], a1[4], b0[4], b1[4];
        #pragma unroll
        for (int mi = 0; mi < 4; ++mi) {
            a0[mi] = *(const bf16x8*)&As[aoff + mi * 1024 + c0];
            a1[mi] = *(const bf16x8*)&As[aoff + mi * 1024 + c1];
        }
        #pragma unroll
        for (int nj = 0; nj < 4; ++nj) {
            b0[nj] = *(const bf16x8*)&Bs[boff + nj * 1024 + c0];
            b1[nj] = *(const bf16x8*)&Bs[boff + nj * 1024 + c1];
        }
        __syncthreads();
        if (kt + 1 < 32) STAGE((kt + 1) * 64);
        #pragma unroll
        for (int mi = 0; mi < 4; ++mi)
            #pragma unroll
            for (int nj = 0; nj < 4; ++nj) {
                acc[mi][nj] = mf(a0[mi], b0[nj], acc[mi][nj]);
                acc[mi][nj] = mf(a1[mi], b1[nj], acc[mi][nj]);
            }
    }
    #undef STAGE

    #pragma unroll
    for (int mi = 0; mi < 4; ++mi) {
        #pragma unroll
        for (int j = 0; j < 4; ++j) {
            const int grow = tileM * 128 + wm * 64 + mi * 16 + q * 4 + j;
            if (grow < count) {
                const int token = tok_list[e * T_TOK + grow];
                const int kk = kidx_list[e * T_TOK + grow];
                const float gate = gate_list[e * T_TOK + grow];
                float* orow = ypart + ((size_t)token * 4 + kk) * D_MODEL + tileN * 128 + wc * 64 + l15;
                #pragma unroll
                for (int nj = 0; nj < 4; ++nj)
                    orow[nj * 16] = gate * acc[mi][nj][j];
            }
        }
    }
}

// ---------------- Combine: out[t] = sum of the token's 4 gated partials ------
__global__ __launch_bounds__(256) void combine_kernel(
    const float* __restrict__ ypart, float* __restrict__ out)
{
    const int t = blockIdx.x;
    const int d = threadIdx.x * 4;
    const float* p = ypart + (size_t)t * 4 * D_MODEL;
    f32x4 s = *(const f32x4*)(p + d);
    s += *(const f32x4*)(p + D_MODEL + d);
    s += *(const f32x4*)(p + 2 * D_MODEL + d);
    s += *(const f32x4*)(p + 3 * D_MODEL + d);
    *(f32x4*)(out + (size_t)t * D_MODEL + d) = s;
}

extern "C" void kernel_launch(void* const* d_in, const int* in_sizes, int n_in,
                              void* d_out, int out_size, void* d_ws, size_t ws_size,
                              hipStream_t stream)
{
    const float* x   = (const float*)d_in[0];   // [4096, 1024]
    const float* rw  = (const float*)d_in[1];   // [16, 1024]
    const float* wsw = (const float*)d_in[2];   // [16, 4096, 1024]
    const float* w2s = (const float*)d_in[3];   // [16, 1024, 2048]
    float* out = (float*)d_out;                 // [4096, 1024] fp32

    char* wsb = (char*)d_ws;
    int* counts        = (int*)wsb;                                  // 64 B
    int* prefix        = (int*)(wsb + 128);                          // 17 ints
    int* tok_list      = (int*)(wsb + 1024);                         // 256 KB
    float* gate_list   = (float*)(wsb + 1024 + E_EXP * T_TOK * 4);   // 256 KB
    unsigned* choices  = (unsigned*)(wsb + 544u * 1024);             // 16 KB
    float* gate4       = (float*)(wsb + 576u * 1024);                // 64 KB
    int* kidx_list     = (int*)(wsb + 640u * 1024);                  // 256 KB
    __bf16* x_bf       = (__bf16*)(wsb + (1u << 20));                // [1, 9) MB
    __bf16* act        = (__bf16*)(wsb + (12u << 20));               // [12, 96) MB
    __bf16* ws_bf      = (__bf16*)(wsb + (96u << 20));               // [96, 230) MB — dead after gemm1
    float* ypart       = (float*)(wsb + (160u << 20));               // [160, 227) MB, written by gemm2

    // w2_bf placement: fused path needs a region disjoint from live ws_bf.
    const bool fuse_w2 = (ws_size >= (300ull << 20));
    __bf16* w2_bf = fuse_w2 ? (__bf16*)(wsb + (232u << 20))          // [232, 296) MB
                            : (__bf16*)(wsb + (96u << 20));          // alias (serial path)

    // fused: router (1024 blocks) + x cvt (256) + ws cvt (2048)
    router_fused_kernel<<<dim3(3328), 256, 0, stream>>>(x, rw, choices, gate4, x_bf, wsw, ws_bf);
    build_lists_kernel<<<dim3(E_EXP), 256, 0, stream>>>(choices, gate4, counts, tok_list, gate_list, kidx_list);
    prefix_kernel<<<1, 64, 0, stream>>>(counts, prefix);

    if (fuse_w2) {
        // gemm1 (8192 blocks) + w2 cvt tail (2048 blocks) in ONE dispatch
        gemm1_kernel<<<dim3(8192 + 2048), 256, 0, stream>>>(
            x_bf, ws_bf, counts, prefix, tok_list, act, w2s, w2_bf);
    } else {
        gemm1_kernel<<<dim3(8192), 256, 0, stream>>>(
            x_bf, ws_bf, counts, prefix, tok_list, act, w2s, w2_bf);
        cvt_kernel<<<8192, 256, 0, stream>>>(w2s, w2_bf, E_EXP * D_MODEL * I_DIM / 8);
    }

    gemm2_kernel<<<dim3(2048), 256, 0, stream>>>(
        act, w2_bf, counts, prefix, tok_list, gate_list, kidx_list, ypart);

    combine_kernel<<<dim3(T_TOK), 256, 0, stream>>>(ypart, out);
}